// Round 12
// baseline (5358.815 us; speedup 1.0000x reference)
//
#include <hip/hip_runtime.h>

// All ops except the two deliberate FMAs below are per-op rounded.
#pragma clang fp contract(off)

#define BATCH 32
#define NPTS 100000
#define NGROUP 2048
#define NBLK_PER_BATCH 8
#define NPB (NPTS / NBLK_PER_BATCH)   /* 12500 points per block */
#define TPB 512
#define NPT 25                        /* ceil(12500/512) points per thread */
#define TAIL (NPB - (NPT - 1) * TPB)  /* 212 */

typedef unsigned long long u64;
typedef unsigned int u32;

static_assert(NPB * NBLK_PER_BATCH == NPTS, "block split must be exact");
static_assert(NPT * TPB >= NPB, "per-thread capacity");

// Guaranteed single-instruction IEEE ops (immune to compiler contraction
// decisions in either direction).
__device__ __forceinline__ float fsub_x(float a, float b) {
  float r; asm("v_sub_f32 %0, %1, %2" : "=v"(r) : "v"(a), "v"(b)); return r;
}
__device__ __forceinline__ float fmul_x(float a, float b) {
  float r; asm("v_mul_f32 %0, %1, %2" : "=v"(r) : "v"(a), "v"(b)); return r;
}
__device__ __forceinline__ float fma_x(float a, float b, float c) {
  float r; asm("v_fma_f32 %0, %1, %2, %3" : "=v"(r) : "v"(a), "v"(b), "v"(c)); return r;
}

// XLA-contracted distance: the multiply of each squared term is fused into
// the reduce-add that consumes it (XLA reduce order 0,1,2):
//   d = fma(dz,dz, fma(dy,dy, dx*dx))
// This is the jax/XLA evaluation of sum((x-c)**2, -1); the jax-precomputed
// expected (ref=np is its numpy serialization) was produced this way.

// Spin-exchange protocol (R1/R2), proven bit-equivalent to grid.sync (R3/R4):
// per iteration each block atomicExch-publishes {dist,tag,~idx} into its slot,
// then wave 0's lanes 0-7 poll the 8 slots until all tags match t. Slots are
// memset to 0xFF each call (tag 0x7FFF never matches t <= 2046). All 256
// blocks are co-resident (launch_bounds 512,2) so the spin cannot deadlock.
__global__ __launch_bounds__(TPB, 2)
void fps_kernel(const float* __restrict__ xyz,
                const int* __restrict__ finit,
                float* __restrict__ out,
                u64* __restrict__ slots)
{
  const int blk  = blockIdx.x;
  const int b    = blk & (BATCH - 1);   // batch id
  const int j    = blk >> 5;            // sub-block 0..7 within batch
  const int tid  = threadIdx.x;
  const int lane = tid & 63;
  const int wid  = tid >> 6;

  __shared__ float sval[TPB / 64];
  __shared__ int   sidx[TPB / 64];
  __shared__ int   s_win;

  const float* xb = xyz + (size_t)b * NPTS * 3;
  const int base = j * NPB;

  // register-resident point coords + f32 running min distance
  float px[NPT], py[NPT], pz[NPT], pd[NPT];
#pragma unroll
  for (int i = 0; i < NPT; ++i) {
    const bool valid = (i < NPT - 1) || (tid < TAIL);
    const int p  = valid ? (tid + i * TPB) : 0;
    const int gp = base + p;
    px[i] = xb[gp * 3 + 0];
    py[i] = xb[gp * 3 + 1];
    pz[i] = xb[gp * 3 + 2];
    pd[i] = valid ? 1.0e10f : -1.0f;   // invalid pads can never win argmax
  }

  int cur = finit[b];   // int32 delivery established (R8 == R5, R1 == R2)

  float cx = xb[cur * 3 + 0], cy = xb[cur * 3 + 1], cz = xb[cur * 3 + 2];

  u64* batchSlots = slots + (size_t)b * NBLK_PER_BATCH * 2;

  for (int t = 0; t < NGROUP; ++t) {
    // record current farthest (pre-update), matching lax.scan's y output
    if (j == 0 && tid == 0) {
      float* o = out + ((size_t)b * NGROUP + t) * 3;
      o[0] = cx; o[1] = cy; o[2] = cz;
    }
    if (t == NGROUP - 1) break;

    // --- distance min-update + thread-local argmax (first-max wins) ---
    float bestv = -1.0f;
    int   besti = 0x7fffffff;
#pragma unroll
    for (int i = 0; i < NPT; ++i) {
      const bool valid = (i < NPT - 1) || (tid < TAIL);
      const float dx = fsub_x(px[i], cx);
      const float dy = fsub_x(py[i], cy);
      const float dz = fsub_x(pz[i], cz);
      const float d  = fma_x(dz, dz, fma_x(dy, dy, fmul_x(dx, dx)));
      if (valid) {
        const float nd = fminf(pd[i], d);   // jnp.minimum
        pd[i] = nd;
        if (nd > bestv) { bestv = nd; besti = base + tid + i * TPB; }  // strict >: lowest idx
      }
    }

    // --- wave-level argmax reduce (lowest index on ties) ---
#pragma unroll
    for (int off = 32; off > 0; off >>= 1) {
      const float ov = __shfl_xor(bestv, off, 64);
      const int   oi = __shfl_xor(besti, off, 64);
      if (ov > bestv || (ov == bestv && oi < besti)) { bestv = ov; besti = oi; }
    }
    if (lane == 0) { sval[wid] = bestv; sidx[wid] = besti; }
    __syncthreads();

    if (wid == 0) {
      const int nw = TPB / 64;
      float v  = (lane < nw) ? sval[lane] : -1.0f;
      int   ix = (lane < nw) ? sidx[lane] : 0x7fffffff;
#pragma unroll
      for (int off = nw / 2; off > 0; off >>= 1) {
        const float ov = __shfl_xor(v, off, 64);
        const int   oi = __shfl_xor(ix, off, 64);
        if (ov > v || (ov == v && oi < ix)) { v = ov; ix = oi; }
      }

      // --- cross-block all-to-all exchange, tag-validated ---
      if (lane == 0) {
        const u64 packed = ((u64)__float_as_uint(v) << 32)
                         | ((u64)(u32)(t & 0x7FFF) << 17)
                         | (u64)((~(u32)ix) & 0x1FFFFu);   // ~idx: lower idx wins ties
        atomicExch(batchSlots + (size_t)j * 2 + (t & 1), packed);
      }
      u64 got = 0;
      const u32 want = (u32)(t & 0x7FFF);
      u64* rp = batchSlots + (size_t)lane * 2 + (t & 1);
      bool ok;
      do {
        got = (lane < NBLK_PER_BATCH) ? atomicAdd(rp, 0ull) : 0ull;  // device-scope read
        ok  = (lane >= NBLK_PER_BATCH) || (((u32)(got >> 17) & 0x7FFFu) == want);
      } while (!__all(ok));

      u64 bp = (lane < NBLK_PER_BATCH) ? got : 0ull;
#pragma unroll
      for (int off = 4; off > 0; off >>= 1) {
        const u64 o = __shfl_xor(bp, off, 64);
        if (o > bp) bp = o;
      }
      if (lane == 0) s_win = (int)((~(u32)bp) & 0x1FFFFu);
    }
    __syncthreads();

    cur = s_win;
    // reload centroid coords from read-only xyz (always coherent)
    cx = xb[cur * 3 + 0];
    cy = xb[cur * 3 + 1];
    cz = xb[cur * 3 + 2];
  }
}

extern "C" void kernel_launch(void* const* d_in, const int* in_sizes, int n_in,
                              void* d_out, int out_size, void* d_ws, size_t ws_size,
                              hipStream_t stream) {
  const float* xyz   = (const float*)d_in[0];
  const int*   finit = (const int*)d_in[1];
  float*       out   = (float*)d_out;
  u64*         slots = (u64*)d_ws;   // 32*8*2 u64 = 4 KB of exchange slots

  // Invalidate all exchange slots every call (tag bits -> 0x7FFF, never a
  // valid iteration tag). Capture-safe.
  hipMemsetAsync(d_ws, 0xFF, (size_t)BATCH * NBLK_PER_BATCH * 2 * sizeof(u64),
                 stream);

  fps_kernel<<<dim3(BATCH * NBLK_PER_BATCH), dim3(TPB), 0, stream>>>(xyz, finit, out, slots);
}